// Round 5
// baseline (293.584 us; speedup 1.0000x reference)
//
#include <hip/hip_runtime.h>
#include <hip/hip_bf16.h>
#include <math.h>

typedef __attribute__((ext_vector_type(8))) short bf16x8;
typedef __attribute__((ext_vector_type(4))) float f32x4;
typedef __hip_bfloat16 bf16_t;

#define NEG_INF_V -100000000.0f

__device__ __forceinline__ void gload16(const void* g, void* l) {
  __builtin_amdgcn_global_load_lds(
      (const __attribute__((address_space(1))) unsigned int*)g,
      (__attribute__((address_space(3))) unsigned int*)l, 16, 0, 0);
}

// swizzled ds_read of one bf16x8: row r (8 16B-slots per 64-short row),
// logical slot c (0..7). Physical slot = c ^ (r&7).
__device__ __forceinline__ bf16x8 swzread(const short* base, int r, int c) {
  return *(const bf16x8*)(base + ((r * 8 + (c ^ (r & 7))) << 3));
}

// ---------- feats NCHW fp32 -> x_pad [B][66][66][256] bf16 (borders zeroed) ----------
__global__ __launch_bounds__(256) void pad_cast_k(
    const float* __restrict__ feats, bf16_t* __restrict__ x_pad) {
  __shared__ float s[64][65];
  const int t = threadIdx.x;
  const int y = blockIdx.x, c0 = blockIdx.y * 64, b = blockIdx.z;
  bf16_t* xp = x_pad + (size_t)b * (66 * 66 * 256) + (size_t)y * 66 * 256 + c0;
  if (y == 0 || y == 65) {
    for (int i = t; i < 66 * 64; i += 256) {
      int px = i >> 6, ci = i & 63;
      xp[(size_t)px * 256 + ci] = __float2bfloat16(0.f);
    }
    return;
  }
  const float* fb = feats + ((size_t)b * 256 + c0) * 4096 + (size_t)(y - 1) * 64;
  for (int i = t; i < 64 * 64; i += 256) {
    int ci = i >> 6, x = i & 63;
    s[ci][x] = fb[(size_t)ci * 4096 + x];
  }
  __syncthreads();
  if (t < 128) {  // px = 0 and px = 65 borders
    int px = (t >> 6) * 65, ci = t & 63;
    xp[(size_t)px * 256 + ci] = __float2bfloat16(0.f);
  }
  for (int i = t; i < 64 * 64; i += 256) {
    int xi = i >> 6, ci = i & 63;
    xp[(size_t)(xi + 1) * 256 + ci] = __float2bfloat16(s[ci][xi]);
  }
}

// ---------- all weight casts fused ----------
__global__ __launch_bounds__(256) void castw_all_k(
    const float* __restrict__ w0, const float* __restrict__ w1,
    const float* __restrict__ wk, const float* __restrict__ wf,
    bf16_t* __restrict__ o0, bf16_t* __restrict__ o1,
    bf16_t* __restrict__ ok, bf16_t* __restrict__ of) {
  const int bid = blockIdx.x, t = threadIdx.x;
  if (bid < 512) {
    int which = bid >> 8, co = bid & 255;
    const float* ws = which ? w1 : w0;
    bf16_t* wd = which ? o1 : o0;
#pragma unroll
    for (int k = 0; k < 9; ++k)
      wd[(size_t)co * 2304 + k * 256 + t] = __float2bfloat16(ws[((size_t)co * 256 + t) * 9 + k]);
  } else {
    int i = (bid - 512) * 256 + t;
    if (i < 257 * 256) ok[i] = __float2bfloat16(wk[i]);
    else { int j = i - 257 * 256; if (j < 256 * 256) of[j] = __float2bfloat16(wf[j]); }
  }
}

// ---------- conv3x3 (+bias+relu) implicit GEMM, 2-phase dbuf, BK=128 ----------
// grid (64 y-rows, 4 co-tiles of 64, B); tile 64px x 64co; K = 9*256 = 18 steps
// LDS tile layout: [kh][64 rows][8 slots of 8 shorts], slot XOR-swizzled by row
__global__ __launch_bounds__(256) void conv3x3_mfma_k(
    const bf16_t* __restrict__ xpad, const bf16_t* __restrict__ wr,
    const float* __restrict__ bias, bf16_t* __restrict__ out,
    int out_row_stride, int out_base, long out_bstride) {
  __shared__ __align__(16) short ldsA[2][8192];
  __shared__ __align__(16) short ldsB[2][8192];
  const int t = threadIdx.x, w = t >> 6, lane = t & 63;
  const int y = blockIdx.x, co0 = blockIdx.y * 64, b = blockIdx.z;
  const bf16_t* xb = xpad + (size_t)b * (66 * 66 * 256);
  const int wm = w >> 1, wn = w & 1;
  f32x4 acc[2][2] = {};

  int arow[4], akh[4], alsl[4];
#pragma unroll
  for (int pp = 0; pp < 4; ++pp) {
    int u = (pp * 4 + w) * 64 + lane;
    int gr = u >> 3, slot = u & 7;
    arow[pp] = gr & 63; akh[pp] = gr >> 6;
    alsl[pp] = (slot ^ (gr & 7)) * 8;
  }
  const int fr = lane & 15, fc = lane >> 4;

  auto stage = [&](int ks, int buf) {
    int kpos = ks >> 1, ck0 = (ks & 1) * 128;
    int ky = (kpos * 11) >> 5, kx = kpos - 3 * ky;
#pragma unroll
    for (int pp = 0; pp < 4; ++pp) {
      gload16(xb + ((size_t)(y + ky) * 66 + arow[pp] + kx) * 256 + kpos * 0 + ck0 + akh[pp] * 64 + alsl[pp]
                 + (size_t)kpos * 0,  // ci index only
              &ldsA[buf][(pp * 4 + w) * 512]);
      gload16(wr + (size_t)(co0 + arow[pp]) * 2304 + kpos * 256 + ck0 + akh[pp] * 64 + alsl[pp],
              &ldsB[buf][(pp * 4 + w) * 512]);
    }
  };
  auto compute = [&](int buf) {
#pragma unroll
    for (int kk = 0; kk < 4; ++kk) {
      const short* bA = &ldsA[buf][(kk >> 1) * 4096];
      const short* bB = &ldsB[buf][(kk >> 1) * 4096];
      int c = (kk & 1) * 4 + fc;
      bf16x8 af[2], bfr[2];
#pragma unroll
      for (int m = 0; m < 2; ++m) af[m] = swzread(bA, wm * 32 + m * 16 + fr, c);
#pragma unroll
      for (int n = 0; n < 2; ++n) bfr[n] = swzread(bB, wn * 32 + n * 16 + fr, c);
#pragma unroll
      for (int m = 0; m < 2; ++m)
#pragma unroll
        for (int n = 0; n < 2; ++n)
          acc[m][n] = __builtin_amdgcn_mfma_f32_16x16x32_bf16(af[m], bfr[n], acc[m][n], 0, 0, 0);
    }
  };

  stage(0, 0);
  __syncthreads();
  for (int ks = 0; ks < 17; ++ks) {
    stage(ks + 1, (ks + 1) & 1);
    compute(ks & 1);
    __syncthreads();
  }
  compute(1);

  bf16_t* ob = out + (size_t)b * out_bstride;
  float bv[2];
#pragma unroll
  for (int n = 0; n < 2; ++n) bv[n] = bias[co0 + wn * 32 + n * 16 + fr];
#pragma unroll
  for (int m = 0; m < 2; ++m)
#pragma unroll
    for (int r = 0; r < 4; ++r) {
      int x = wm * 32 + m * 16 + fc * 4 + r;
      size_t ra = (size_t)out_base + (size_t)y * out_row_stride + (size_t)x * 256 + co0 + wn * 32 + fr;
#pragma unroll
      for (int n = 0; n < 2; ++n) {
        float v = acc[m][n][r] + bv[n];
        ob[ra + n * 16] = __float2bfloat16(fmaxf(v, 0.f));
      }
    }
}

// ---------- 1x1 conv GEMM, single-stage BK=256 (one barrier) ----------
template <bool KER>
__global__ __launch_bounds__(256) void conv1x1_mfma_k(
    const bf16_t* __restrict__ in, const bf16_t* __restrict__ wt,
    const float* __restrict__ bias, bf16_t* __restrict__ outw,
    float* __restrict__ outkb, int A0, int AS, long in_bstride, int comax) {
  __shared__ __align__(16) short ldsA[16384];
  __shared__ __align__(16) short ldsB[16384];
  const int t = threadIdx.x, w = t >> 6, lane = t & 63;
  const int y = blockIdx.x, co0 = blockIdx.y * 64, b = blockIdx.z;
  const bf16_t* inb = in + (size_t)b * in_bstride;
  const int wm = w >> 1, wn = w & 1;
  f32x4 acc[2][2] = {};
  const int fr = lane & 15, fc = lane >> 4;

#pragma unroll
  for (int pp = 0; pp < 8; ++pp) {
    int u = (pp * 4 + w) * 64 + lane;
    int gr = u >> 3, slot = u & 7;
    int row = gr & 63, kh = gr >> 6;
    int lsl = (slot ^ (gr & 7)) * 8;
    gload16(inb + (size_t)A0 + (size_t)y * AS + (size_t)row * 256 + kh * 64 + lsl,
            &ldsA[(pp * 4 + w) * 512]);
    gload16(wt + (size_t)min(co0 + row, comax - 1) * 256 + kh * 64 + lsl,
            &ldsB[(pp * 4 + w) * 512]);
  }
  __syncthreads();
#pragma unroll
  for (int kk = 0; kk < 8; ++kk) {
    const short* bA = &ldsA[(kk >> 1) * 4096];
    const short* bB = &ldsB[(kk >> 1) * 4096];
    int c = (kk & 1) * 4 + fc;
    bf16x8 af[2], bfr[2];
#pragma unroll
    for (int m = 0; m < 2; ++m) af[m] = swzread(bA, wm * 32 + m * 16 + fr, c);
#pragma unroll
    for (int n = 0; n < 2; ++n) bfr[n] = swzread(bB, wn * 32 + n * 16 + fr, c);
#pragma unroll
    for (int m = 0; m < 2; ++m)
#pragma unroll
      for (int n = 0; n < 2; ++n)
        acc[m][n] = __builtin_amdgcn_mfma_f32_16x16x32_bf16(af[m], bfr[n], acc[m][n], 0, 0, 0);
  }

#pragma unroll
  for (int m = 0; m < 2; ++m)
#pragma unroll
    for (int r = 0; r < 4; ++r) {
      int x = wm * 32 + m * 16 + fc * 4 + r;
      int prow = y * 64 + x;
#pragma unroll
      for (int n = 0; n < 2; ++n) {
        int co = co0 + wn * 32 + n * 16 + fr;
        float v = acc[m][n][r] + bias[min(co, comax - 1)];
        if (KER) {
          if (co < 256) outw[((size_t)b * 4096 + prow) * 256 + co] = __float2bfloat16(v);
          else if (co == 256) outkb[(size_t)b * 4096 + prow] = v;
        } else {
          outw[((size_t)b * 4096 + prow) * 256 + co] = __float2bfloat16(v);
        }
      }
    }
}

// ---------- logits GEMM + mask + write + fused dice partials ----------
// grid (32 p-tiles, 32 q-tiles, B); tile 128p x 128q; BK=64, 4 steps, 2-phase
// waves 2x2, each wave 64x64 output (4x4 fragments) -> reads/MFMA = 0.5
__global__ __launch_bounds__(256) void logits_mfma_k(
    const bf16_t* __restrict__ kwt, const float* __restrict__ kb,
    const bf16_t* __restrict__ fft, const float* __restrict__ masks,
    const int* __restrict__ layouts, float* __restrict__ out,
    float* __restrict__ partial) {
  __shared__ __align__(16) short ldsA[2][8192];
  __shared__ __align__(16) short ldsB[2][8192];
  const int t = threadIdx.x, w = t >> 6, lane = t & 63;
  const int p0 = blockIdx.x * 128, q0 = blockIdx.y * 128, b = blockIdx.z;
  const bf16_t* ab = kwt + (size_t)b * (4096 * 256);
  const bf16_t* bb = fft + (size_t)b * (4096 * 256);
  const int wm = w >> 1, wn = w & 1;
  f32x4 acc[4][4] = {};

  int grow[4], glsl[4];
#pragma unroll
  for (int pp = 0; pp < 4; ++pp) {
    int u = (pp * 4 + w) * 64 + lane;
    int gr = u >> 3, slot = u & 7;
    grow[pp] = gr;                       // 0..127
    glsl[pp] = (slot ^ (gr & 7)) * 8;
  }
  const int fr = lane & 15, fc = lane >> 4;

  auto stage = [&](int ks, int buf) {
    int cik = ks * 64;
#pragma unroll
    for (int pp = 0; pp < 4; ++pp) {
      gload16(ab + (size_t)(p0 + grow[pp]) * 256 + cik + glsl[pp], &ldsA[buf][(pp * 4 + w) * 512]);
      gload16(bb + (size_t)(q0 + grow[pp]) * 256 + cik + glsl[pp], &ldsB[buf][(pp * 4 + w) * 512]);
    }
  };
  auto compute = [&](int buf) {
#pragma unroll
    for (int kk = 0; kk < 2; ++kk) {
      int c = kk * 4 + fc;
      bf16x8 af[4], bfr[4];
#pragma unroll
      for (int m = 0; m < 4; ++m) af[m] = swzread(ldsA[buf], wm * 64 + m * 16 + fr, c);
#pragma unroll
      for (int n = 0; n < 4; ++n) bfr[n] = swzread(ldsB[buf], wn * 64 + n * 16 + fr, c);
#pragma unroll
      for (int m = 0; m < 4; ++m)
#pragma unroll
        for (int n = 0; n < 4; ++n)
          acc[m][n] = __builtin_amdgcn_mfma_f32_16x16x32_bf16(af[m], bfr[n], acc[m][n], 0, 0, 0);
    }
  };

  stage(0, 0);
  __syncthreads();
  for (int ks = 0; ks < 3; ++ks) {
    stage(ks + 1, (ks + 1) & 1);
    compute(ks & 1);
    __syncthreads();
  }
  compute(1);

  float mq[4];
  int layq[4];
#pragma unroll
  for (int n = 0; n < 4; ++n) {
    int q = q0 + wn * 64 + n * 16 + fr;
    mq[n] = masks[b * 4096 + q];
    layq[n] = layouts[b * 4096 + q];
  }
  float sl[16];
#pragma unroll
  for (int i = 0; i < 16; ++i) sl[i] = 0.f;
  float* outb = out + (size_t)b * 4096 * 4096;
#pragma unroll
  for (int m = 0; m < 4; ++m) {
#pragma unroll
    for (int r = 0; r < 4; ++r) {
      int p = p0 + wm * 64 + m * 16 + fc * 4 + r;
      float kbv = kb[b * 4096 + p];
      int layp = layouts[b * 4096 + p];
      float s = 0.f;
      size_t ra = (size_t)p * 4096 + q0 + wn * 64 + fr;
#pragma unroll
      for (int n = 0; n < 4; ++n) {
        float lg = (mq[n] > 0.f) ? (acc[m][n][r] + kbv) : NEG_INF_V;
        outb[ra + n * 16] = lg;
        float pz = 1.f / (1.f + __expf(-lg));
        float lab = (layp == layq[n]) ? 1.f : 0.f;
        float d = 2.f * pz * lab / (pz * pz + lab + 0.002f);
        s += (1.f - d) * mq[n];
      }
      sl[m * 4 + r] = s;
    }
  }
#pragma unroll
  for (int i = 0; i < 16; ++i) {
    float v = sl[i];
    v += __shfl_xor(v, 1); v += __shfl_xor(v, 2);
    v += __shfl_xor(v, 4); v += __shfl_xor(v, 8);
    sl[i] = v;
  }
  if (fr == 0) {
    int qt = blockIdx.y * 2 + wn;
#pragma unroll
    for (int m = 0; m < 4; ++m)
#pragma unroll
      for (int r = 0; r < 4; ++r) {
        int p = p0 + wm * 64 + m * 16 + fc * 4 + r;
        partial[((size_t)b * 4096 + p) * 64 + qt] = sl[m * 4 + r];
      }
  }
}

// ---------- loss stage 1: per-p rowsum * mp, atomic accumulate ----------
__global__ __launch_bounds__(256) void rowsum_k(
    const float* __restrict__ partial, const float* __restrict__ masks,
    float* __restrict__ accum) {
  const int t = threadIdx.x, w = t >> 6, lane = t & 63;
  const int idx = blockIdx.x * 256 + t;
  const int b = idx >> 12;
  const float* pp = partial + (size_t)idx * 64;
  float s = 0.f;
#pragma unroll
  for (int k = 0; k < 64; ++k) s += pp[k];
  float mp = masks[idx];
  float num = s * mp;
#pragma unroll
  for (int off = 32; off; off >>= 1) {
    num += __shfl_down(num, off);
    mp += __shfl_down(mp, off);
  }
  __shared__ float sn[4], sm[4];
  if (lane == 0) { sn[w] = num; sm[w] = mp; }
  __syncthreads();
  if (t == 0) {
    atomicAdd(&accum[b * 2], sn[0] + sn[1] + sn[2] + sn[3]);
    atomicAdd(&accum[b * 2 + 1], sm[0] + sm[1] + sm[2] + sm[3]);
  }
}

__global__ void loss_final_k(const float* __restrict__ accum, float* __restrict__ out_loss) {
  if (threadIdx.x == 0) {
    float l0 = accum[0] / (accum[1] * accum[1] + 1e-5f);
    float l1 = accum[2] / (accum[3] * accum[3] + 1e-5f);
    out_loss[0] = 0.5f * (l0 + l1);
  }
}

extern "C" void kernel_launch(void* const* d_in, const int* in_sizes, int n_in,
                              void* d_out, int out_size, void* d_ws, size_t ws_size,
                              hipStream_t stream) {
  const float* feats = (const float*)d_in[0];
  const float* masks = (const float*)d_in[1];
  const int* layouts = (const int*)d_in[2];
  const float* w_pre0 = (const float*)d_in[3];
  const float* b_pre0 = (const float*)d_in[4];
  const float* w_pre1 = (const float*)d_in[5];
  const float* b_pre1 = (const float*)d_in[6];
  const float* w_kernel = (const float*)d_in[7];
  const float* b_kernel = (const float*)d_in[8];
  const float* w_feats = (const float*)d_in[9];
  const float* b_feats = (const float*)d_in[10];

  bf16_t* x_pad = (bf16_t*)d_ws;                 // 2*1115136
  bf16_t* h1p = x_pad + 2 * 1115136;             // 2*1115136
  bf16_t* h2 = h1p + 2 * 1115136;                // 2*1048576
  bf16_t* w0r = h2 + 2 * 1048576;                // 589824
  bf16_t* w1r = w0r + 589824;                    // 589824
  bf16_t* wkb = w1r + 589824;                    // 65792
  bf16_t* wfb = wkb + 65792;                     // 65536
  bf16_t* kwt = wfb + 65536;                     // 2*1048576
  bf16_t* fft = kwt + 2 * 1048576;               // 2*1048576
  float* kb = (float*)(fft + 2 * 1048576);       // 8192
  float* partial = kb + 8192;                    // 524288
  float* accum = partial + 524288;               // 4
  float* out = (float*)d_out;

  // h1p borders must be zero (conv#1 writes interior only); accum zero
  hipMemsetAsync(h1p, 0, (size_t)2 * 1115136 * sizeof(bf16_t), stream);
  hipMemsetAsync(accum, 0, 4 * sizeof(float), stream);

  pad_cast_k<<<dim3(66, 4, 2), 256, 0, stream>>>(feats, x_pad);
  castw_all_k<<<dim3(1026), 256, 0, stream>>>(w_pre0, w_pre1, w_kernel, w_feats,
                                              w0r, w1r, wkb, wfb);

  conv3x3_mfma_k<<<dim3(64, 4, 2), 256, 0, stream>>>(
      x_pad, w0r, b_pre0, h1p, 66 * 256, 67 * 256, 1115136L);
  conv3x3_mfma_k<<<dim3(64, 4, 2), 256, 0, stream>>>(
      h1p, w1r, b_pre1, h2, 64 * 256, 0, 1048576L);

  conv1x1_mfma_k<true><<<dim3(64, 5, 2), 256, 0, stream>>>(
      h2, wkb, b_kernel, kwt, kb, 0, 16384, 1048576L, 257);
  conv1x1_mfma_k<false><<<dim3(64, 4, 2), 256, 0, stream>>>(
      x_pad, wfb, b_feats, fft, nullptr, 67 * 256, 66 * 256, 1115136L, 256);

  logits_mfma_k<<<dim3(32, 32, 2), 256, 0, stream>>>(
      kwt, kb, fft, masks, layouts, out, partial);

  rowsum_k<<<dim3(32), 256, 0, stream>>>(partial, masks, accum);
  loss_final_k<<<1, 64, 0, stream>>>(accum, out + (size_t)2 * 4096 * 4096);
}

// Round 6
// 268.440 us; speedup vs baseline: 1.0937x; 1.0937x over previous
//
#include <hip/hip_runtime.h>
#include <hip/hip_bf16.h>
#include <math.h>

typedef __attribute__((ext_vector_type(8))) short bf16x8;
typedef __attribute__((ext_vector_type(4))) float f32x4;
typedef __hip_bfloat16 bf16_t;

#define NEG_INF_V -100000000.0f

__device__ __forceinline__ void gload16(const void* g, void* l) {
  __builtin_amdgcn_global_load_lds(
      (const __attribute__((address_space(1))) unsigned int*)g,
      (__attribute__((address_space(3))) unsigned int*)l, 16, 0, 0);
}

// swizzled ds_read of one bf16x8: row r (8 16B-slots per 64-short row),
// logical slot c (0..7). Physical slot = c ^ (r&7).
__device__ __forceinline__ bf16x8 swzread(const short* base, int r, int c) {
  return *(const bf16x8*)(base + ((r * 8 + (c ^ (r & 7))) << 3));
}

// ---------- feats NCHW fp32 -> x_pad [B][66][66][256] bf16 (borders zeroed) ----------
__global__ __launch_bounds__(256) void pad_cast_k(
    const float* __restrict__ feats, bf16_t* __restrict__ x_pad) {
  __shared__ float s[64][65];
  const int t = threadIdx.x;
  const int y = blockIdx.x, c0 = blockIdx.y * 64, b = blockIdx.z;
  bf16_t* xp = x_pad + (size_t)b * (66 * 66 * 256) + (size_t)y * 66 * 256 + c0;
  if (y == 0 || y == 65) {
    for (int i = t; i < 66 * 64; i += 256) {
      int px = i >> 6, ci = i & 63;
      xp[(size_t)px * 256 + ci] = __float2bfloat16(0.f);
    }
    return;
  }
  const float* fb = feats + ((size_t)b * 256 + c0) * 4096 + (size_t)(y - 1) * 64;
  for (int i = t; i < 64 * 64; i += 256) {
    int ci = i >> 6, x = i & 63;
    s[ci][x] = fb[(size_t)ci * 4096 + x];
  }
  __syncthreads();
  if (t < 128) {  // px = 0 and px = 65 borders
    int px = (t >> 6) * 65, ci = t & 63;
    xp[(size_t)px * 256 + ci] = __float2bfloat16(0.f);
  }
  for (int i = t; i < 64 * 64; i += 256) {
    int xi = i >> 6, ci = i & 63;
    xp[(size_t)(xi + 1) * 256 + ci] = __float2bfloat16(s[ci][xi]);
  }
}

// ---------- all weight casts fused ----------
__global__ __launch_bounds__(256) void castw_all_k(
    const float* __restrict__ w0, const float* __restrict__ w1,
    const float* __restrict__ wk, const float* __restrict__ wf,
    bf16_t* __restrict__ o0, bf16_t* __restrict__ o1,
    bf16_t* __restrict__ ok, bf16_t* __restrict__ of) {
  const int bid = blockIdx.x, t = threadIdx.x;
  if (bid < 512) {
    int which = bid >> 8, co = bid & 255;
    const float* ws = which ? w1 : w0;
    bf16_t* wd = which ? o1 : o0;
#pragma unroll
    for (int k = 0; k < 9; ++k)
      wd[(size_t)co * 2304 + k * 256 + t] = __float2bfloat16(ws[((size_t)co * 256 + t) * 9 + k]);
  } else {
    int i = (bid - 512) * 256 + t;
    if (i < 257 * 256) ok[i] = __float2bfloat16(wk[i]);
    else { int j = i - 257 * 256; if (j < 256 * 256) of[j] = __float2bfloat16(wf[j]); }
  }
}

// ---------- conv3x3 (+bias+relu) implicit GEMM, 2-phase dbuf, BK=128 ----------
__global__ __launch_bounds__(256) void conv3x3_mfma_k(
    const bf16_t* __restrict__ xpad, const bf16_t* __restrict__ wr,
    const float* __restrict__ bias, bf16_t* __restrict__ out,
    int out_row_stride, int out_base, long out_bstride) {
  __shared__ __align__(16) short ldsA[2][8192];
  __shared__ __align__(16) short ldsB[2][8192];
  const int t = threadIdx.x, w = t >> 6, lane = t & 63;
  const int y = blockIdx.x, co0 = blockIdx.y * 64, b = blockIdx.z;
  const bf16_t* xb = xpad + (size_t)b * (66 * 66 * 256);
  const int wm = w >> 1, wn = w & 1;
  f32x4 acc[2][2] = {};

  int arow[4], akh[4], alsl[4];
#pragma unroll
  for (int pp = 0; pp < 4; ++pp) {
    int u = (pp * 4 + w) * 64 + lane;
    int gr = u >> 3, slot = u & 7;
    arow[pp] = gr & 63; akh[pp] = gr >> 6;
    alsl[pp] = (slot ^ (gr & 7)) * 8;
  }
  const int fr = lane & 15, fc = lane >> 4;

  auto stage = [&](int ks, int buf) {
    int kpos = ks >> 1, ck0 = (ks & 1) * 128;
    int ky = (kpos * 11) >> 5, kx = kpos - 3 * ky;
#pragma unroll
    for (int pp = 0; pp < 4; ++pp) {
      gload16(xb + ((size_t)(y + ky) * 66 + arow[pp] + kx) * 256 + ck0 + akh[pp] * 64 + alsl[pp],
              &ldsA[buf][(pp * 4 + w) * 512]);
      gload16(wr + (size_t)(co0 + arow[pp]) * 2304 + kpos * 256 + ck0 + akh[pp] * 64 + alsl[pp],
              &ldsB[buf][(pp * 4 + w) * 512]);
    }
  };
  auto compute = [&](int buf) {
#pragma unroll
    for (int kk = 0; kk < 4; ++kk) {
      const short* bA = &ldsA[buf][(kk >> 1) * 4096];
      const short* bB = &ldsB[buf][(kk >> 1) * 4096];
      int c = (kk & 1) * 4 + fc;
      bf16x8 af[2], bfr[2];
#pragma unroll
      for (int m = 0; m < 2; ++m) af[m] = swzread(bA, wm * 32 + m * 16 + fr, c);
#pragma unroll
      for (int n = 0; n < 2; ++n) bfr[n] = swzread(bB, wn * 32 + n * 16 + fr, c);
#pragma unroll
      for (int m = 0; m < 2; ++m)
#pragma unroll
        for (int n = 0; n < 2; ++n)
          acc[m][n] = __builtin_amdgcn_mfma_f32_16x16x32_bf16(af[m], bfr[n], acc[m][n], 0, 0, 0);
    }
  };

  stage(0, 0);
  __syncthreads();
  for (int ks = 0; ks < 17; ++ks) {
    stage(ks + 1, (ks + 1) & 1);
    compute(ks & 1);
    __syncthreads();
  }
  compute(1);

  bf16_t* ob = out + (size_t)b * out_bstride;
  float bv[2];
#pragma unroll
  for (int n = 0; n < 2; ++n) bv[n] = bias[co0 + wn * 32 + n * 16 + fr];
#pragma unroll
  for (int m = 0; m < 2; ++m)
#pragma unroll
    for (int r = 0; r < 4; ++r) {
      int x = wm * 32 + m * 16 + fc * 4 + r;
      size_t ra = (size_t)out_base + (size_t)y * out_row_stride + (size_t)x * 256 + co0 + wn * 32 + fr;
#pragma unroll
      for (int n = 0; n < 2; ++n) {
        float v = acc[m][n][r] + bv[n];
        ob[ra + n * 16] = __float2bfloat16(fmaxf(v, 0.f));
      }
    }
}

// ---------- 1x1 conv GEMM, single-stage BK=256 (one barrier) ----------
template <bool KER>
__global__ __launch_bounds__(256) void conv1x1_mfma_k(
    const bf16_t* __restrict__ in, const bf16_t* __restrict__ wt,
    const float* __restrict__ bias, bf16_t* __restrict__ outw,
    float* __restrict__ outkb, int A0, int AS, long in_bstride, int comax) {
  __shared__ __align__(16) short ldsA[16384];
  __shared__ __align__(16) short ldsB[16384];
  const int t = threadIdx.x, w = t >> 6, lane = t & 63;
  const int y = blockIdx.x, co0 = blockIdx.y * 64, b = blockIdx.z;
  const bf16_t* inb = in + (size_t)b * in_bstride;
  const int wm = w >> 1, wn = w & 1;
  f32x4 acc[2][2] = {};
  const int fr = lane & 15, fc = lane >> 4;

#pragma unroll
  for (int pp = 0; pp < 8; ++pp) {
    int u = (pp * 4 + w) * 64 + lane;
    int gr = u >> 3, slot = u & 7;
    int row = gr & 63, kh = gr >> 6;
    int lsl = (slot ^ (gr & 7)) * 8;
    gload16(inb + (size_t)A0 + (size_t)y * AS + (size_t)row * 256 + kh * 64 + lsl,
            &ldsA[(pp * 4 + w) * 512]);
    gload16(wt + (size_t)min(co0 + row, comax - 1) * 256 + kh * 64 + lsl,
            &ldsB[(pp * 4 + w) * 512]);
  }
  __syncthreads();
#pragma unroll
  for (int kk = 0; kk < 8; ++kk) {
    const short* bA = &ldsA[(kk >> 1) * 4096];
    const short* bB = &ldsB[(kk >> 1) * 4096];
    int c = (kk & 1) * 4 + fc;
    bf16x8 af[2], bfr[2];
#pragma unroll
    for (int m = 0; m < 2; ++m) af[m] = swzread(bA, wm * 32 + m * 16 + fr, c);
#pragma unroll
    for (int n = 0; n < 2; ++n) bfr[n] = swzread(bB, wn * 32 + n * 16 + fr, c);
#pragma unroll
    for (int m = 0; m < 2; ++m)
#pragma unroll
      for (int n = 0; n < 2; ++n)
        acc[m][n] = __builtin_amdgcn_mfma_f32_16x16x32_bf16(af[m], bfr[n], acc[m][n], 0, 0, 0);
  }

#pragma unroll
  for (int m = 0; m < 2; ++m)
#pragma unroll
    for (int r = 0; r < 4; ++r) {
      int x = wm * 32 + m * 16 + fc * 4 + r;
      int prow = y * 64 + x;
#pragma unroll
      for (int n = 0; n < 2; ++n) {
        int co = co0 + wn * 32 + n * 16 + fr;
        float v = acc[m][n][r] + bias[min(co, comax - 1)];
        if (KER) {
          if (co < 256) outw[((size_t)b * 4096 + prow) * 256 + co] = __float2bfloat16(v);
          else if (co == 256) outkb[(size_t)b * 4096 + prow] = v;
        } else {
          outw[((size_t)b * 4096 + prow) * 256 + co] = __float2bfloat16(v);
        }
      }
    }
}

// ---------- logits GEMM + mask + coalesced write + fused dice partials ----------
// grid (32 p-tiles, 32 q-tiles, B); tile 128p x 128q; BK=64, 2-phase dbuf.
// Epilogue: LDS-staged fp32 store (2 halves of 64 rows x 128 cols, stride 132),
// dice via  sum_mq - sum_match d*mq,  d = 2u/(1+1.002u^2), u = 1+exp(-lg).
__global__ __launch_bounds__(256) void logits_mfma_k(
    const bf16_t* __restrict__ kwt, const float* __restrict__ kb,
    const bf16_t* __restrict__ fft, const float* __restrict__ masks,
    const int* __restrict__ layouts, float* __restrict__ out,
    float* __restrict__ partial) {
  __shared__ __align__(16) short ldsbuf[32768];   // 64 KB, GEMM bufs + store staging
  short* ldsA0 = ldsbuf;            // [2][8192]
  short* ldsB0 = ldsbuf + 16384;    // [2][8192]
  float* ldsf = (float*)ldsbuf;     // 16384 floats for epilogue staging
  const int t = threadIdx.x, w = t >> 6, lane = t & 63;
  const int p0 = blockIdx.x * 128, q0 = blockIdx.y * 128, b = blockIdx.z;
  const bf16_t* ab = kwt + (size_t)b * (4096 * 256);
  const bf16_t* bb = fft + (size_t)b * (4096 * 256);
  const int wm = w >> 1, wn = w & 1;
  f32x4 acc[4][4] = {};

  int grow[4], glsl[4];
#pragma unroll
  for (int pp = 0; pp < 4; ++pp) {
    int u = (pp * 4 + w) * 64 + lane;
    int gr = u >> 3, slot = u & 7;
    grow[pp] = gr;
    glsl[pp] = (slot ^ (gr & 7)) * 8;
  }
  const int fr = lane & 15, fc = lane >> 4;

  auto stage = [&](int ks, int buf) {
    int cik = ks * 64;
#pragma unroll
    for (int pp = 0; pp < 4; ++pp) {
      gload16(ab + (size_t)(p0 + grow[pp]) * 256 + cik + glsl[pp],
              &ldsA0[buf * 8192 + (pp * 4 + w) * 512]);
      gload16(bb + (size_t)(q0 + grow[pp]) * 256 + cik + glsl[pp],
              &ldsB0[buf * 8192 + (pp * 4 + w) * 512]);
    }
  };
  auto compute = [&](int buf) {
#pragma unroll
    for (int kk = 0; kk < 2; ++kk) {
      int c = kk * 4 + fc;
      bf16x8 af[4], bfr[4];
#pragma unroll
      for (int m = 0; m < 4; ++m) af[m] = swzread(&ldsA0[buf * 8192], wm * 64 + m * 16 + fr, c);
#pragma unroll
      for (int n = 0; n < 4; ++n) bfr[n] = swzread(&ldsB0[buf * 8192], wn * 64 + n * 16 + fr, c);
#pragma unroll
      for (int m = 0; m < 4; ++m)
#pragma unroll
        for (int n = 0; n < 4; ++n)
          acc[m][n] = __builtin_amdgcn_mfma_f32_16x16x32_bf16(af[m], bfr[n], acc[m][n], 0, 0, 0);
    }
  };

  stage(0, 0);
  __syncthreads();
  for (int ks = 0; ks < 3; ++ks) {
    stage(ks + 1, (ks + 1) & 1);
    compute(ks & 1);
    __syncthreads();
  }
  compute(1);

  // per-q metadata for this wave's 64-q half
  float mq[4];
  int layq[4];
#pragma unroll
  for (int n = 0; n < 4; ++n) {
    int q = q0 + wn * 64 + n * 16 + fr;
    mq[n] = masks[b * 4096 + q];
    layq[n] = layouts[b * 4096 + q];
  }
  // wave-uniform sum of mq over the 64 q's of this half
  float mqsum = mq[0] + mq[1] + mq[2] + mq[3];
  mqsum += __shfl_xor(mqsum, 1); mqsum += __shfl_xor(mqsum, 2);
  mqsum += __shfl_xor(mqsum, 4); mqsum += __shfl_xor(mqsum, 8);

  float sl[16];
  float* outb = out + (size_t)b * 4096 * 4096;
  __syncthreads();   // all GEMM LDS reads done; safe to reuse as ldsf

  for (int half = 0; half < 2; ++half) {
    if (wm == half) {
#pragma unroll
      for (int m = 0; m < 4; ++m) {
#pragma unroll
        for (int r = 0; r < 4; ++r) {
          int pl = m * 16 + fc * 4 + r;
          int p = p0 + wm * 64 + pl;
          float kbv = kb[b * 4096 + p];
          int layp = layouts[b * 4096 + p];
          float dsum = 0.f;
#pragma unroll
          for (int n = 0; n < 4; ++n) {
            float lg = (mq[n] > 0.f) ? (acc[m][n][r] + kbv) : NEG_INF_V;
            ldsf[pl * 132 + wn * 64 + n * 16 + fr] = lg;
            float E = __expf(fminf(-lg, 87.f));        // clamp: no inf/NaN path
            float u = 1.f + E;
            float den = fmaf(1.002f * u, u, 1.f);      // 1 + 1.002 u^2
            float d = 2.f * u * __builtin_amdgcn_rcpf(den);
            dsum += (layp == layq[n]) ? mq[n] * d : 0.f;
          }
          sl[m * 4 + r] = dsum;
        }
      }
    }
    __syncthreads();
    // all 256 threads: store 64 rows x 128 cols as float4 (512B/row segments)
#pragma unroll
    for (int j = 0; j < 8; ++j) {
      int row = w * 16 + j * 2 + (lane >> 5);
      int colf = (lane & 31) * 4;
      float4 v = *(float4*)&ldsf[row * 132 + colf];
      int p = p0 + half * 64 + row;
      *(float4*)&outb[(size_t)p * 4096 + q0 + colf] = v;
    }
    __syncthreads();
  }

  // reduce dice partials over fr and write (value = mqsum - sum_match d*mq)
#pragma unroll
  for (int i = 0; i < 16; ++i) {
    float v = sl[i];
    v += __shfl_xor(v, 1); v += __shfl_xor(v, 2);
    v += __shfl_xor(v, 4); v += __shfl_xor(v, 8);
    sl[i] = v;
  }
  if (fr == 0) {
    int qt = blockIdx.y * 2 + wn;
#pragma unroll
    for (int m = 0; m < 4; ++m)
#pragma unroll
      for (int r = 0; r < 4; ++r) {
        int p = p0 + wm * 64 + m * 16 + fc * 4 + r;
        partial[((size_t)b * 4096 + p) * 64 + qt] = mqsum - sl[m * 4 + r];
      }
  }
}

// ---------- loss stage 1: per-p rowsum * mp, atomic accumulate ----------
__global__ __launch_bounds__(256) void rowsum_k(
    const float* __restrict__ partial, const float* __restrict__ masks,
    float* __restrict__ accum) {
  const int t = threadIdx.x, w = t >> 6, lane = t & 63;
  const int idx = blockIdx.x * 256 + t;
  const int b = idx >> 12;
  const float* pp = partial + (size_t)idx * 64;
  float s = 0.f;
#pragma unroll
  for (int k = 0; k < 64; ++k) s += pp[k];
  float mp = masks[idx];
  float num = s * mp;
#pragma unroll
  for (int off = 32; off; off >>= 1) {
    num += __shfl_down(num, off);
    mp += __shfl_down(mp, off);
  }
  __shared__ float sn[4], sm[4];
  if (lane == 0) { sn[w] = num; sm[w] = mp; }
  __syncthreads();
  if (t == 0) {
    atomicAdd(&accum[b * 2], sn[0] + sn[1] + sn[2] + sn[3]);
    atomicAdd(&accum[b * 2 + 1], sm[0] + sm[1] + sm[2] + sm[3]);
  }
}

__global__ void loss_final_k(const float* __restrict__ accum, float* __restrict__ out_loss) {
  if (threadIdx.x == 0) {
    float l0 = accum[0] / (accum[1] * accum[1] + 1e-5f);
    float l1 = accum[2] / (accum[3] * accum[3] + 1e-5f);
    out_loss[0] = 0.5f * (l0 + l1);
  }
}

extern "C" void kernel_launch(void* const* d_in, const int* in_sizes, int n_in,
                              void* d_out, int out_size, void* d_ws, size_t ws_size,
                              hipStream_t stream) {
  const float* feats = (const float*)d_in[0];
  const float* masks = (const float*)d_in[1];
  const int* layouts = (const int*)d_in[2];
  const float* w_pre0 = (const float*)d_in[3];
  const float* b_pre0 = (const float*)d_in[4];
  const float* w_pre1 = (const float*)d_in[5];
  const float* b_pre1 = (const float*)d_in[6];
  const float* w_kernel = (const float*)d_in[7];
  const float* b_kernel = (const float*)d_in[8];
  const float* w_feats = (const float*)d_in[9];
  const float* b_feats = (const float*)d_in[10];

  bf16_t* x_pad = (bf16_t*)d_ws;                 // 2*1115136
  bf16_t* h1p = x_pad + 2 * 1115136;             // 2*1115136
  bf16_t* h2 = h1p + 2 * 1115136;                // 2*1048576
  bf16_t* w0r = h2 + 2 * 1048576;                // 589824
  bf16_t* w1r = w0r + 589824;                    // 589824
  bf16_t* wkb = w1r + 589824;                    // 65792
  bf16_t* wfb = wkb + 65792;                     // 65536
  bf16_t* kwt = wfb + 65536;                     // 2*1048576
  bf16_t* fft = kwt + 2 * 1048576;               // 2*1048576
  float* kb = (float*)(fft + 2 * 1048576);       // 8192
  float* partial = kb + 8192;                    // 524288
  float* accum = partial + 524288;               // 4
  float* out = (float*)d_out;

  // h1p borders must be zero (conv#1 writes interior only); accum zero
  hipMemsetAsync(h1p, 0, (size_t)2 * 1115136 * sizeof(bf16_t), stream);
  hipMemsetAsync(accum, 0, 4 * sizeof(float), stream);

  pad_cast_k<<<dim3(66, 4, 2), 256, 0, stream>>>(feats, x_pad);
  castw_all_k<<<dim3(1026), 256, 0, stream>>>(w_pre0, w_pre1, w_kernel, w_feats,
                                              w0r, w1r, wkb, wfb);

  conv3x3_mfma_k<<<dim3(64, 4, 2), 256, 0, stream>>>(
      x_pad, w0r, b_pre0, h1p, 66 * 256, 67 * 256, 1115136L);
  conv3x3_mfma_k<<<dim3(64, 4, 2), 256, 0, stream>>>(
      h1p, w1r, b_pre1, h2, 64 * 256, 0, 1048576L);

  conv1x1_mfma_k<true><<<dim3(64, 5, 2), 256, 0, stream>>>(
      h2, wkb, b_kernel, kwt, kb, 0, 16384, 1048576L, 257);
  conv1x1_mfma_k<false><<<dim3(64, 4, 2), 256, 0, stream>>>(
      x_pad, wfb, b_feats, fft, nullptr, 67 * 256, 66 * 256, 1115136L, 256);

  logits_mfma_k<<<dim3(32, 32, 2), 256, 0, stream>>>(
      kwt, kb, fft, masks, layouts, out, partial);

  rowsum_k<<<dim3(32), 256, 0, stream>>>(partial, masks, accum);
  loss_final_k<<<1, 64, 0, stream>>>(accum, out + (size_t)2 * 4096 * 4096);
}